// Round 4
// baseline (4402.582 us; speedup 1.0000x reference)
//
#include <hip/hip_runtime.h>

// LSTM last-hidden + projection. B=256, T=4096, F=32, H=128, 4H=512.
// 64 WGs x 512 threads (8 waves, 2/SIMD); WG g owns batches [4g,4g+4) at MFMA
// A-rows {0,4,8,12}. z(4x512) = [x_t|h](4x160) @ [W;U](160x512), mfma 16x16x32 f16.
// R3 finding: MFMA dependent-use latency ~240cy made 5-deep acc chains the
// bottleneck. R4: all 16 h-MFMAs are independent depth-1 partials (C=0), reduced
// with scalar adds (only element [0] of each f32x4 is used). x_t enters via
// direct global->register A-fragments; its 4 kc=0 MFMAs issue pre-barrier for
// t+1, filling the pipe during the activation/barrier shadow.

#define TT 4096
#define FF 32
#define HH 128
#define NG 512

typedef float f32x4 __attribute__((ext_vector_type(4)));
typedef _Float16 h16x8 __attribute__((ext_vector_type(8)));

__device__ __forceinline__ float sigmoid_f(float x) {
    return __builtin_amdgcn_rcpf(1.f + __expf(-x));
}
__device__ __forceinline__ float tanh_f(float x) {
    // saturates correctly: exp->inf => 1, exp->0 => -1
    return 1.f - 2.f * __builtin_amdgcn_rcpf(__expf(2.f * x) + 1.f);
}

__global__ __launch_bounds__(512, 2)
void lstm_seq_kernel(const float* __restrict__ x,        // (B,T,F)
                     const int*   __restrict__ seq_lens, // (B)
                     const float* __restrict__ W,        // (F,4H)
                     const float* __restrict__ U,        // (H,4H)
                     const float* __restrict__ bias,     // (4H)
                     const float* __restrict__ Wf,       // (H)
                     const float* __restrict__ bfp,      // (1)
                     float* __restrict__ out)            // (B)
{
    // h-only A staging (k>=32): A[par][kc-1][slot][j] == A[m=slot&15][k=kc*32+(slot>>4)*8+j]
    __shared__ _Float16 A[2][4][64][8];
    __shared__ float outAcc[4];

    const int tid  = threadIdx.x;
    const int lane = tid & 63;
    const int w    = tid >> 6;     // wave 0..7
    const int c    = lane & 15;    // n-col within tile
    const int q    = lane >> 4;    // quad 0..3 -> this lane's batch
    const int b0   = blockIdx.x * 4;
    const int hc   = w * 16 + c;   // this lane's LSTM cell (0..127)

    {
        _Float16* p = &A[0][0][0][0];
        for (int i = tid; i < 2 * 4 * 64 * 8; i += 512) p[i] = (_Float16)0.f;
        if (tid < 4) outAcc[tid] = 0.f;
    }

    const int sl0 = seq_lens[b0 + 0], sl1 = seq_lens[b0 + 1];
    const int sl2 = seq_lens[b0 + 2], sl3 = seq_lens[b0 + 3];
    const int gmax = max(max(sl0, sl1), max(sl2, sl3));
    const int slq  = seq_lens[b0 + q];

    // register-resident weights: wave w -> tiles {8j+w}, j = gate i,f,g,o; n = j*128+hc
    // B-frag: lane holds B[k = kc*32 + q*8 + e][n]
    h16x8 bh[4][5];
    #pragma unroll
    for (int j = 0; j < 4; ++j) {
        const int n = j * 128 + hc;
        #pragma unroll
        for (int kc = 0; kc < 5; ++kc) {
            #pragma unroll
            for (int e = 0; e < 8; ++e) {
                const int k = kc * 32 + q * 8 + e;
                float v = (k < FF) ? W[k * NG + n] : U[(k - FF) * NG + n];
                bh[j][kc][e] = (_Float16)v;
            }
        }
    }

    const float bi0 = bias[hc], bi1 = bias[HH + hc];
    const float bi2 = bias[2 * HH + hc], bi3 = bias[3 * HH + hc];
    const float wfv = Wf[hc];
    const int kk    = FF + hc;                        // K-position of this h element
    const int wkc   = (kk >> 5) - 1;                  // 0..3
    const int wslot = ((kk >> 3) & 3) * 16 + 4 * q;   // batch q at row 4q
    const int wj    = kk & 7;

    // x A-fragment: lane needs A[m=c][k=q*8+e]; real rows m=4b -> lanes c%4==0, batch=c>>2
    const bool xact = ((c & 3) == 0);
    const float* xrow = x + (size_t)(b0 + (c >> 2)) * TT * FF + q * 8;

    const f32x4 zero4 = {0.f, 0.f, 0.f, 0.f};

    // x_0 fragment -> kc=0 partials
    f32x4 accX[4];
    {
        float4 xa = {0,0,0,0}, xb = {0,0,0,0};
        if (xact) {
            xa = *(const float4*)(xrow);
            xb = *(const float4*)(xrow + 4);
        }
        h16x8 xf = { (_Float16)xa.x, (_Float16)xa.y, (_Float16)xa.z, (_Float16)xa.w,
                     (_Float16)xb.x, (_Float16)xb.y, (_Float16)xb.z, (_Float16)xb.w };
        #pragma unroll
        for (int j = 0; j < 4; ++j)
            accX[j] = __builtin_amdgcn_mfma_f32_16x16x32_f16(xf, bh[j][0], zero4, 0, 0, 0);
    }
    __syncthreads();

    float cc = 0.f, hh = 0.f;

    for (int t = 0; t < gmax; ++t) {
        const int par = t & 1, pnx = par ^ 1;

        // prefetch x_{t+1} (clamped; last-iter value unused)
        const int tload = (t + 1 < TT) ? (t + 1) : (TT - 1);
        float4 xa = {0,0,0,0}, xb = {0,0,0,0};
        if (xact) {
            const float* p = xrow + (size_t)tload * FF;
            xa = *(const float4*)(p);
            xb = *(const float4*)(p + 4);
        }

        // 16 independent depth-1 MFMAs (kc=1..4 x 4 gates), C=0
        h16x8 a1 = *(const h16x8*)&A[par][0][lane][0];
        h16x8 a2 = *(const h16x8*)&A[par][1][lane][0];
        h16x8 a3 = *(const h16x8*)&A[par][2][lane][0];
        h16x8 a4 = *(const h16x8*)&A[par][3][lane][0];
        f32x4 p1[4], p2[4], p3[4], p4[4];
        #pragma unroll
        for (int j = 0; j < 4; ++j)
            p1[j] = __builtin_amdgcn_mfma_f32_16x16x32_f16(a1, bh[j][1], zero4, 0, 0, 0);
        #pragma unroll
        for (int j = 0; j < 4; ++j)
            p2[j] = __builtin_amdgcn_mfma_f32_16x16x32_f16(a2, bh[j][2], zero4, 0, 0, 0);
        #pragma unroll
        for (int j = 0; j < 4; ++j)
            p3[j] = __builtin_amdgcn_mfma_f32_16x16x32_f16(a3, bh[j][3], zero4, 0, 0, 0);
        #pragma unroll
        for (int j = 0; j < 4; ++j)
            p4[j] = __builtin_amdgcn_mfma_f32_16x16x32_f16(a4, bh[j][4], zero4, 0, 0, 0);

        // scalar reduction: only element [0] (row = 4q+0 = batch q) is real
        float z0 = accX[0][0] + p1[0][0] + p2[0][0] + p3[0][0] + p4[0][0] + bi0;
        float z1 = accX[1][0] + p1[1][0] + p2[1][0] + p3[1][0] + p4[1][0] + bi1;
        float z2 = accX[2][0] + p1[2][0] + p2[2][0] + p3[2][0] + p4[2][0] + bi2;
        float z3 = accX[3][0] + p1[3][0] + p2[3][0] + p3[3][0] + p4[3][0] + bi3;

        float gi = sigmoid_f(z0);
        float gf = sigmoid_f(z1);
        float gg = tanh_f(z2);
        float go = sigmoid_f(z3);
        float cn = gf * cc + gi * gg;
        float hn = go * tanh_f(cn);
        const bool upd = (t < slq);
        cc = upd ? cn : cc;
        hh = upd ? hn : hh;
        A[pnx][wkc][wslot][wj] = (_Float16)hh;

        // next x fragment -> kc=0 partials for t+1 (issues during act/barrier shadow)
        h16x8 xf = { (_Float16)xa.x, (_Float16)xa.y, (_Float16)xa.z, (_Float16)xa.w,
                     (_Float16)xb.x, (_Float16)xb.y, (_Float16)xb.z, (_Float16)xb.w };
        #pragma unroll
        for (int j = 0; j < 4; ++j)
            accX[j] = __builtin_amdgcn_mfma_f32_16x16x32_f16(xf, bh[j][0], zero4, 0, 0, 0);

        __syncthreads();
    }

    // epilogue: out[b] = h @ Wf + bf
    float p = hh * wfv;
    p += __shfl_down(p, 8, 16);
    p += __shfl_down(p, 4, 16);
    p += __shfl_down(p, 2, 16);
    p += __shfl_down(p, 1, 16);
    if (c == 0) atomicAdd(&outAcc[q], p);
    __syncthreads();
    if (tid < 4) out[b0 + tid] = outAcc[tid] + bfp[0];
}

extern "C" void kernel_launch(void* const* d_in, const int* in_sizes, int n_in,
                              void* d_out, int out_size, void* d_ws, size_t ws_size,
                              hipStream_t stream) {
    const float* x        = (const float*)d_in[0];
    const int*   seq_lens = (const int*)d_in[1];
    const float* W        = (const float*)d_in[2];
    const float* U        = (const float*)d_in[3];
    const float* bias     = (const float*)d_in[4];
    const float* Wf       = (const float*)d_in[5];
    const float* bfp      = (const float*)d_in[6];
    float* out = (float*)d_out;

    lstm_seq_kernel<<<dim3(64), dim3(512), 0, stream>>>(x, seq_lens, W, U, bias, Wf, bfp, out);
}

// Round 5
// 3019.044 us; speedup vs baseline: 1.4583x; 1.4583x over previous
//
#include <hip/hip_runtime.h>

// LSTM last-hidden + projection. B=256, T=4096, F=32, H=128, 4H=512.
// 64 WGs x 512 threads (8 waves, 2/SIMD); WG g owns batches [4g,4g+4) at MFMA
// A-rows {0,4,8,12}. z(4x512) = [x_t|h](4x160) @ [W;U](160x512), mfma 16x16x32 f16.
// Model (fit R1-R4): MFMA issue ~19.4cy/SIMD, dependent-use latency L~240cy,
// VALU-reads of MFMA dests are expensive (R4: 20 reads => +530cy/step).
// R5: per gate, TWO depth-2 chains (accumulate in the MFMA pipe, join with ONE
// add/gate): chainP = kc1->kc2 seeded with C=accX (x-part + bias, computed
// pre-barrier from register x_t), chainQ = kc3->kc4 seeded C=0.
// x double-prefetched (t+2) -> HBM latency fully covered.

#define TT 4096
#define FF 32
#define HH 128
#define NG 512

typedef float f32x4 __attribute__((ext_vector_type(4)));
typedef _Float16 h16x8 __attribute__((ext_vector_type(8)));

__device__ __forceinline__ float sigmoid_f(float x) {
    return __builtin_amdgcn_rcpf(1.f + __expf(-x));
}
__device__ __forceinline__ float tanh_f(float x) {
    // saturates correctly: exp->inf => 1, exp->0 => -1
    return 1.f - 2.f * __builtin_amdgcn_rcpf(__expf(2.f * x) + 1.f);
}

__global__ __launch_bounds__(512, 2)
void lstm_seq_kernel(const float* __restrict__ x,        // (B,T,F)
                     const int*   __restrict__ seq_lens, // (B)
                     const float* __restrict__ W,        // (F,4H)
                     const float* __restrict__ U,        // (H,4H)
                     const float* __restrict__ bias,     // (4H)
                     const float* __restrict__ Wf,       // (H)
                     const float* __restrict__ bfp,      // (1)
                     float* __restrict__ out)            // (B)
{
    // h-only A staging: A[par][kc-1][slot][j] == A[m=slot&15][k=kc*32+(slot>>4)*8+j]
    __shared__ _Float16 A[2][4][64][8];
    __shared__ float outAcc[4];

    const int tid  = threadIdx.x;
    const int lane = tid & 63;
    const int w    = tid >> 6;     // wave 0..7
    const int c    = lane & 15;    // n-col within tile
    const int q    = lane >> 4;    // quad 0..3 -> this lane's batch
    const int b0   = blockIdx.x * 4;
    const int hc   = w * 16 + c;   // this lane's LSTM cell (0..127)

    {
        _Float16* p = &A[0][0][0][0];
        for (int i = tid; i < 2 * 4 * 64 * 8; i += 512) p[i] = (_Float16)0.f;
        if (tid < 4) outAcc[tid] = 0.f;
    }

    const int sl0 = seq_lens[b0 + 0], sl1 = seq_lens[b0 + 1];
    const int sl2 = seq_lens[b0 + 2], sl3 = seq_lens[b0 + 3];
    const int gmax = max(max(sl0, sl1), max(sl2, sl3));
    const int slq  = seq_lens[b0 + q];

    // register-resident weights: wave w -> tiles {8j+w}, j = gate i,f,g,o; n = j*128+hc
    // B-frag: lane holds B[k = kc*32 + q*8 + e][n]
    h16x8 bh[4][5];
    #pragma unroll
    for (int j = 0; j < 4; ++j) {
        const int n = j * 128 + hc;
        #pragma unroll
        for (int kc = 0; kc < 5; ++kc) {
            #pragma unroll
            for (int e = 0; e < 8; ++e) {
                const int k = kc * 32 + q * 8 + e;
                float v = (k < FF) ? W[k * NG + n] : U[(k - FF) * NG + n];
                bh[j][kc][e] = (_Float16)v;
            }
        }
    }

    // bias folded into accX's C operand (only element [0] is ever read)
    f32x4 biasC[4];
    #pragma unroll
    for (int j = 0; j < 4; ++j) {
        const float bv = bias[j * HH + hc];
        f32x4 t = {bv, bv, bv, bv};
        biasC[j] = t;
    }
    const float wfv = Wf[hc];
    const int kk    = FF + hc;                        // K-position of this h element
    const int wkc   = (kk >> 5) - 1;                  // 0..3
    const int wslot = ((kk >> 3) & 3) * 16 + 4 * q;   // batch q at row 4q
    const int wj    = kk & 7;

    // x A-fragment: lane needs A[m=c][k=q*8+e]; real rows m=4b -> lanes c%4==0, batch=c>>2
    const bool xact = ((c & 3) == 0);
    const float* xrow = x + (size_t)(b0 + (c >> 2)) * TT * FF + q * 8;

    const f32x4 zero4 = {0.f, 0.f, 0.f, 0.f};

    // pre-loop: accX for t=0 (x_0·W + bias), prefetch x_1 into registers
    f32x4 accX[4];
    {
        float4 xa = {0,0,0,0}, xb = {0,0,0,0};
        if (xact) {
            xa = *(const float4*)(xrow);
            xb = *(const float4*)(xrow + 4);
        }
        h16x8 xf = { (_Float16)xa.x, (_Float16)xa.y, (_Float16)xa.z, (_Float16)xa.w,
                     (_Float16)xb.x, (_Float16)xb.y, (_Float16)xb.z, (_Float16)xb.w };
        #pragma unroll
        for (int j = 0; j < 4; ++j)
            accX[j] = __builtin_amdgcn_mfma_f32_16x16x32_f16(xf, bh[j][0], biasC[j], 0, 0, 0);
    }
    float4 cxa = {0,0,0,0}, cxb = {0,0,0,0};    // x_{t+1} (registers)
    if (xact) {
        const float* p = xrow + (size_t)((1 < TT) ? 1 : TT - 1) * FF;
        cxa = *(const float4*)(p);
        cxb = *(const float4*)(p + 4);
    }
    __syncthreads();

    float cc = 0.f, hh = 0.f;

    for (int t = 0; t < gmax; ++t) {
        const int par = t & 1, pnx = par ^ 1;

        // post-barrier: h A-fragments (4 x ds_read_b128)
        h16x8 a1 = *(const h16x8*)&A[par][0][lane][0];
        h16x8 a2 = *(const h16x8*)&A[par][1][lane][0];
        h16x8 a3 = *(const h16x8*)&A[par][2][lane][0];
        h16x8 a4 = *(const h16x8*)&A[par][3][lane][0];

        // issue x_{t+2} load early (2-step latency cover)
        float4 nxa = {0,0,0,0}, nxb = {0,0,0,0};
        if (xact) {
            const int tl = (t + 2 < TT) ? (t + 2) : (TT - 1);
            const float* p = xrow + (size_t)tl * FF;
            nxa = *(const float4*)(p);
            nxb = *(const float4*)(p + 4);
        }

        // two depth-2 chains per gate; all 8 first-links independent
        f32x4 pc[4], qc[4];
        #pragma unroll
        for (int j = 0; j < 4; ++j)
            qc[j] = __builtin_amdgcn_mfma_f32_16x16x32_f16(a3, bh[j][3], zero4, 0, 0, 0);
        #pragma unroll
        for (int j = 0; j < 4; ++j)
            pc[j] = __builtin_amdgcn_mfma_f32_16x16x32_f16(a1, bh[j][1], accX[j], 0, 0, 0);
        #pragma unroll
        for (int j = 0; j < 4; ++j)
            qc[j] = __builtin_amdgcn_mfma_f32_16x16x32_f16(a4, bh[j][4], qc[j], 0, 0, 0);
        #pragma unroll
        for (int j = 0; j < 4; ++j)
            pc[j] = __builtin_amdgcn_mfma_f32_16x16x32_f16(a2, bh[j][2], pc[j], 0, 0, 0);

        // join (8 VALU reads of MFMA dests) + activation; row 4q+0 = batch q
        float z0 = pc[0][0] + qc[0][0];
        float z1 = pc[1][0] + qc[1][0];
        float z2 = pc[2][0] + qc[2][0];
        float z3 = pc[3][0] + qc[3][0];

        float gi = sigmoid_f(z0);
        float gf = sigmoid_f(z1);
        float gg = tanh_f(z2);
        float go = sigmoid_f(z3);
        float cn = gf * cc + gi * gg;
        float hn = go * tanh_f(cn);
        const bool upd = (t < slq);
        cc = upd ? cn : cc;
        hh = upd ? hn : hh;
        A[pnx][wkc][wslot][wj] = (_Float16)hh;

        // accX for t+1 (x_{t+1}·W + bias), pre-barrier: ready when chains restart
        {
            h16x8 xf = { (_Float16)cxa.x, (_Float16)cxa.y, (_Float16)cxa.z, (_Float16)cxa.w,
                         (_Float16)cxb.x, (_Float16)cxb.y, (_Float16)cxb.z, (_Float16)cxb.w };
            #pragma unroll
            for (int j = 0; j < 4; ++j)
                accX[j] = __builtin_amdgcn_mfma_f32_16x16x32_f16(xf, bh[j][0], biasC[j], 0, 0, 0);
        }
        cxa = nxa; cxb = nxb;

        __syncthreads();
    }

    // epilogue: out[b] = h @ Wf + bf
    float p = hh * wfv;
    p += __shfl_down(p, 8, 16);
    p += __shfl_down(p, 4, 16);
    p += __shfl_down(p, 2, 16);
    p += __shfl_down(p, 1, 16);
    if (c == 0) atomicAdd(&outAcc[q], p);
    __syncthreads();
    if (tid < 4) out[b0 + tid] = outAcc[tid] + bfp[0];
}

extern "C" void kernel_launch(void* const* d_in, const int* in_sizes, int n_in,
                              void* d_out, int out_size, void* d_ws, size_t ws_size,
                              hipStream_t stream) {
    const float* x        = (const float*)d_in[0];
    const int*   seq_lens = (const int*)d_in[1];
    const float* W        = (const float*)d_in[2];
    const float* U        = (const float*)d_in[3];
    const float* bias     = (const float*)d_in[4];
    const float* Wf       = (const float*)d_in[5];
    const float* bfp      = (const float*)d_in[6];
    float* out = (float*)d_out;

    lstm_seq_kernel<<<dim3(64), dim3(512), 0, stream>>>(x, seq_lens, W, U, bias, Wf, bfp, out);
}